// Round 8
// baseline (113.228 us; speedup 1.0000x reference)
//
#include <hip/hip_runtime.h>

#define KS    7
#define H     256
#define W     256
#define STRIP 16                 // output rows per wave
#define WPB   4                  // waves per block (block covers 64 rows)
#define NSTEP (STRIP + KS - 1)   // 22 input rows per strip

typedef float vf4 __attribute__((ext_vector_type(4)));
typedef float vf2 __attribute__((ext_vector_type(2)));

// Build effective 7x7 kernel: w_eff = mk + noise*(noise_eps - mean(noise_eps))
__global__ void GaussianConvBlur_wprep(const float* __restrict__ weight,
                                       const float* __restrict__ noise,
                                       const float* __restrict__ noise_eps,
                                       float* __restrict__ wf) {
    int tid = threadIdx.x;
    if (tid < KS * KS) {
        float m = 0.f;
        #pragma unroll
        for (int i = 0; i < KS * KS; ++i) m += noise_eps[i];
        m *= (1.0f / (KS * KS));
        wf[tid] = weight[tid] + noise[0] * (noise_eps[tid] - m);
    }
}

// LDS-free depthwise 7x7: ring-8 accumulators held as float2 pairs so the
// inner loop issues v_pk_fma_f32 (2x fp32/issue); one aligned float4 load per
// step prefetched 3 ahead; horizontal halo via shfl; non-temporal stores.
__global__ __launch_bounds__(256) void GaussianConvBlur_conv(
        const float* __restrict__ in,
        const float* __restrict__ wfg,
        float* __restrict__ out) {
    const int lane = threadIdx.x & 63;
    const int wid  = threadIdx.x >> 6;

    const int plane = blockIdx.x >> 2;          // 4 blocks per plane
    const int sblk  = blockIdx.x & 3;
    const int s0    = __builtin_amdgcn_readfirstlane((sblk * WPB + wid) * STRIP);

    const float* __restrict__ src = in  + (size_t)plane * (H * W);
    float*       __restrict__ dst = out + (size_t)plane * (H * W);

    // Pin the 49 uniform weights to SGPRs
    float wf[KS * KS];
    #pragma unroll
    for (int i = 0; i < KS * KS; ++i)
        wf[i] = __int_as_float(__builtin_amdgcn_readfirstlane(__float_as_int(wfg[i])));

    const int x4 = lane << 2;                   // aligned offset (floats)
    const bool ln0  = (lane == 0);
    const bool ln63 = (lane == 63);

    vf2 acc[8][2];                              // [slot][lo/hi half of float4]
    #pragma unroll
    for (int i = 0; i < 8; ++i) { acc[i][0] = (vf2)(0.f); acc[i][1] = (vf2)(0.f); }

    vf4 pm[4];                                  // depth-3 prefetch ring

    #define LOADROW(REL, P) do {                                          \
        int ri_  = s0 - 3 + (REL);                                        \
        int ric_ = ri_ < 0 ? 0 : (ri_ > (H - 1) ? (H - 1) : ri_);         \
        pm[P] = *(const vf4*)(src + ric_ * W + x4);                       \
    } while (0)

    #define STEPBODY(REL, U, PF) do {                                     \
        if (PF) LOADROW((REL) + 3, ((U) + 3) & 3);                        \
        const int ri = s0 - 3 + (REL);        /* uniform (SGPR) */        \
        if (ri >= 0 && ri < H) {              /* valid row: accumulate */ \
            vf4 r1 = pm[(U) & 3];                                         \
            /* horizontal halo from neighbor lanes (no loads) */          \
            float hl1 = __shfl_up(r1.y, 1, 64);                           \
            float hl2 = __shfl_up(r1.z, 1, 64);                           \
            float hl3 = __shfl_up(r1.w, 1, 64);                           \
            float hr0 = __shfl_down(r1.x, 1, 64);                         \
            float hr1 = __shfl_down(r1.y, 1, 64);                         \
            float hr2 = __shfl_down(r1.z, 1, 64);                         \
            float s[10];                                                  \
            s[0] = ln0  ? 0.f : hl1;                                      \
            s[1] = ln0  ? 0.f : hl2;                                      \
            s[2] = ln0  ? 0.f : hl3;                                      \
            s[3] = r1.x; s[4] = r1.y; s[5] = r1.z; s[6] = r1.w;           \
            s[7] = ln63 ? 0.f : hr0;                                      \
            s[8] = ln63 ? 0.f : hr1;                                      \
            s[9] = ln63 ? 0.f : hr2;                                      \
            vf2 p[9];                         /* sliding window pairs */  \
            _Pragma("unroll")                                             \
            for (int k = 0; k < 9; ++k) { p[k].x = s[k]; p[k].y = s[k+1]; }\
            _Pragma("unroll")                                             \
            for (int j = 0; j < 7; ++j) {                                 \
                const int slot = ((U) + j) & 7;    /* compile-time */     \
                const int ky   = 6 - j;                                   \
                _Pragma("unroll")                                         \
                for (int kx = 0; kx < 7; ++kx) {                          \
                    const float wv = wf[ky * 7 + kx];                     \
                    vf2 w2 = {wv, wv};                                    \
                    acc[slot][0] = w2 * p[kx]     + acc[slot][0];         \
                    acc[slot][1] = w2 * p[kx + 2] + acc[slot][1];         \
                }                                                         \
            }                                                             \
        }                                                                 \
        const int o = ri - 3;            /* this row completes now */     \
        if (o >= s0) {                                                    \
            vf4 ov;                                                       \
            ov.xy = acc[(U) & 7][0];                                      \
            ov.zw = acc[(U) & 7][1];                                      \
            __builtin_nontemporal_store(ov, (vf4*)(dst + o * W + x4));    \
        }                                                                 \
        acc[(U) & 7][0] = (vf2)(0.f);                                     \
        acc[(U) & 7][1] = (vf2)(0.f);                                     \
    } while (0)

    LOADROW(0, 0);
    LOADROW(1, 1);
    LOADROW(2, 2);

    for (int g = 0; g < 2; ++g) {         // rel = 0..15 (8-unroll, ring%4==0)
        #pragma unroll
        for (int u = 0; u < 8; ++u) STEPBODY(g * 8 + u, u, true);
    }
    #pragma unroll
    for (int u = 0; u < 6; ++u)           // rel = 16..21; last load is rel 21
        STEPBODY(16 + u, u, (u < 3));

    #undef LOADROW
    #undef STEPBODY
}

extern "C" void kernel_launch(void* const* d_in, const int* in_sizes, int n_in,
                              void* d_out, int out_size, void* d_ws, size_t ws_size,
                              hipStream_t stream) {
    const float* x         = (const float*)d_in[0];  // (16,64,256,256)
    const float* weight    = (const float*)d_in[1];  // (64,64,7,7)
    const float* noise     = (const float*)d_in[2];  // scalar
    const float* noise_eps = (const float*)d_in[3];  // (7,7)
    float*       out       = (float*)d_out;
    float*       wf        = (float*)d_ws;           // 49 floats scratch

    GaussianConvBlur_wprep<<<1, 64, 0, stream>>>(weight, noise, noise_eps, wf);

    const int planes = 16 * 64;                       // 1024 planes
    GaussianConvBlur_conv<<<planes * 4, 256, 0, stream>>>(x, wf, out);
}

// Round 9
// 97.406 us; speedup vs baseline: 1.1624x; 1.1624x over previous
//
#include <hip/hip_runtime.h>

#define KS    7
#define H     256
#define W     256
#define STRIP 32                 // output rows per wave
#define WPB   4                  // waves per block (block covers 128 rows)
#define NSTEP (STRIP + KS - 1)   // 38 input rows per strip

typedef float vf4 __attribute__((ext_vector_type(4)));

// lane i <- lane i-1 (lane 0 -> 0): wave_shr:1, bound_ctrl=1
__device__ __forceinline__ float dpp_shr1(float x) {
    return __int_as_float(__builtin_amdgcn_mov_dpp(__float_as_int(x), 0x138, 0xf, 0xf, true));
}
// lane i <- lane i+1 (lane 63 -> 0): wave_shl:1, bound_ctrl=1
__device__ __forceinline__ float dpp_shl1(float x) {
    return __int_as_float(__builtin_amdgcn_mov_dpp(__float_as_int(x), 0x130, 0xf, 0xf, true));
}

// Build effective 7x7 kernel: w_eff = mk + noise*(noise_eps - mean(noise_eps))
__global__ void GaussianConvBlur_wprep(const float* __restrict__ weight,
                                       const float* __restrict__ noise,
                                       const float* __restrict__ noise_eps,
                                       float* __restrict__ wf) {
    int tid = threadIdx.x;
    if (tid < KS * KS) {
        float m = 0.f;
        #pragma unroll
        for (int i = 0; i < KS * KS; ++i) m += noise_eps[i];
        m *= (1.0f / (KS * KS));
        wf[tid] = weight[tid] + noise[0] * (noise_eps[tid] - m);
    }
}

// LDS-free depthwise 7x7: ring-8 fp32 accumulators; ONE aligned float4 load
// per step prefetched 3 ahead; horizontal halo via DPP wave shifts (VALU,
// zero-fill at wave edge = image edge); non-temporal output stores.
__global__ __launch_bounds__(256) void GaussianConvBlur_conv(
        const float* __restrict__ in,
        const float* __restrict__ wfg,
        float* __restrict__ out) {
    const int lane = threadIdx.x & 63;
    const int wid  = threadIdx.x >> 6;

    const int plane = blockIdx.x >> 1;          // 2 blocks per plane
    const int sblk  = blockIdx.x & 1;
    const int s0    = __builtin_amdgcn_readfirstlane((sblk * WPB + wid) * STRIP);

    const float* __restrict__ src = in  + (size_t)plane * (H * W);
    float*       __restrict__ dst = out + (size_t)plane * (H * W);

    // Pin the 49 uniform weights to SGPRs
    float wf[KS * KS];
    #pragma unroll
    for (int i = 0; i < KS * KS; ++i)
        wf[i] = __int_as_float(__builtin_amdgcn_readfirstlane(__float_as_int(wfg[i])));

    const int x4 = lane << 2;                   // aligned offset (floats)

    vf4 acc[8];
    #pragma unroll
    for (int i = 0; i < 8; ++i) acc[i] = (vf4)(0.f);

    vf4 pm[4];                                  // depth-3 prefetch ring

    #define LOADROW(REL, P) do {                                          \
        int ri_  = s0 - 3 + (REL);                                        \
        int ric_ = ri_ < 0 ? 0 : (ri_ > (H - 1) ? (H - 1) : ri_);         \
        pm[P] = *(const vf4*)(src + ric_ * W + x4);                       \
    } while (0)

    #define STEPBODY(REL, U, PF) do {                                     \
        if (PF) LOADROW((REL) + 3, ((U) + 3) & 3);                        \
        const int ri = s0 - 3 + (REL);        /* uniform (SGPR) */        \
        if (ri >= 0 && ri < H) {              /* valid row: accumulate */ \
            vf4 r1 = pm[(U) & 3];                                         \
            float s[10];                                                  \
            s[0] = dpp_shr1(r1.y);            /* lane-1, lane0 -> 0 */    \
            s[1] = dpp_shr1(r1.z);                                        \
            s[2] = dpp_shr1(r1.w);                                        \
            s[3] = r1.x; s[4] = r1.y; s[5] = r1.z; s[6] = r1.w;           \
            s[7] = dpp_shl1(r1.x);            /* lane+1, lane63 -> 0 */   \
            s[8] = dpp_shl1(r1.y);                                        \
            s[9] = dpp_shl1(r1.z);                                        \
            _Pragma("unroll")                                             \
            for (int j = 0; j < 7; ++j) {                                 \
                const int slot = ((U) + j) & 7;    /* compile-time */     \
                const int ky   = 6 - j;                                   \
                _Pragma("unroll")                                         \
                for (int kx = 0; kx < 7; ++kx) {                          \
                    const float wv = wf[ky * 7 + kx];                     \
                    acc[slot].x = fmaf(wv, s[kx],     acc[slot].x);       \
                    acc[slot].y = fmaf(wv, s[kx + 1], acc[slot].y);       \
                    acc[slot].z = fmaf(wv, s[kx + 2], acc[slot].z);       \
                    acc[slot].w = fmaf(wv, s[kx + 3], acc[slot].w);       \
                }                                                         \
            }                                                             \
        }                                                                 \
        const int o = ri - 3;            /* this row completes now */     \
        if (o >= s0)                                                      \
            __builtin_nontemporal_store(acc[(U) & 7],                     \
                                        (vf4*)(dst + o * W + x4));        \
        acc[(U) & 7] = (vf4)(0.f);                                        \
    } while (0)

    LOADROW(0, 0);
    LOADROW(1, 1);
    LOADROW(2, 2);

    for (int g = 0; g < 4; ++g) {         // rel = 0..31 (8-unroll, ring%4==0)
        #pragma unroll
        for (int u = 0; u < 8; ++u) STEPBODY(g * 8 + u, u, true);
    }
    #pragma unroll
    for (int u = 0; u < 6; ++u)           // rel = 32..37; last load is rel 37
        STEPBODY(32 + u, u, (u < 3));

    #undef LOADROW
    #undef STEPBODY
}

extern "C" void kernel_launch(void* const* d_in, const int* in_sizes, int n_in,
                              void* d_out, int out_size, void* d_ws, size_t ws_size,
                              hipStream_t stream) {
    const float* x         = (const float*)d_in[0];  // (16,64,256,256)
    const float* weight    = (const float*)d_in[1];  // (64,64,7,7)
    const float* noise     = (const float*)d_in[2];  // scalar
    const float* noise_eps = (const float*)d_in[3];  // (7,7)
    float*       out       = (float*)d_out;
    float*       wf        = (float*)d_ws;           // 49 floats scratch

    GaussianConvBlur_wprep<<<1, 64, 0, stream>>>(weight, noise, noise_eps, wf);

    const int planes = 16 * 64;                       // 1024 planes
    GaussianConvBlur_conv<<<planes * 2, 256, 0, stream>>>(x, wf, out);
}